// Round 2
// baseline (84.128 us; speedup 1.0000x reference)
//
#include <hip/hip_runtime.h>
#include <math.h>

#define LN_EPS 1e-5f

// Problem constants (fixed by setup_inputs): N=10, K=5, Q=5, H=256, Qtot=50
constexpr int Nn  = 10;
constexpr int Kk  = 5;
constexpr int Hh  = 256;
constexpr int QT  = 50;
constexpr int NP1 = 11;

// ---------------- helpers ----------------
__device__ __forceinline__ float wave64_sum(float v) {
#pragma unroll
    for (int m = 1; m < 64; m <<= 1) v += __shfl_xor(v, m);
    return v;
}
__device__ __forceinline__ float grp16_sum(float v) {
#pragma unroll
    for (int m = 1; m < 16; m <<= 1) v += __shfl_xor(v, m);
    return v;
}

// LayerNorm, 64-lane layout: lane holds h = 4*lane..4*lane+3 (x preloaded)
__device__ __forceinline__ void ln64_x(const float4& x, const float4& g4,
                                       const float4& b4, float y[4]) {
    float s  = x.x + x.y + x.z + x.w;
    float ss = x.x * x.x + x.y * x.y + x.z * x.z + x.w * x.w;
#pragma unroll
    for (int m = 1; m < 64; m <<= 1) { s += __shfl_xor(s, m); ss += __shfl_xor(ss, m); }
    const float mu   = s * (1.0f / (float)Hh);
    const float rstd = rsqrtf(ss * (1.0f / (float)Hh) - mu * mu + LN_EPS);
    y[0] = (x.x - mu) * rstd * g4.x + b4.x;
    y[1] = (x.y - mu) * rstd * g4.y + b4.y;
    y[2] = (x.z - mu) * rstd * g4.z + b4.z;
    y[3] = (x.w - mu) * rstd * g4.w + b4.w;
}

// LayerNorm, 16-lane-group layout: sub-lane holds h = 16*sub..16*sub+15
__device__ __forceinline__ void ln16_row(const float* __restrict__ row,
                                         const float* __restrict__ gamma,
                                         const float* __restrict__ beta,
                                         int sub, float y[16]) {
    const float* p = row + sub * 16;
    float s = 0.f, ss = 0.f;
#pragma unroll
    for (int c = 0; c < 4; ++c) {
        const float4 x = *reinterpret_cast<const float4*>(p + c * 4);
        y[c * 4 + 0] = x.x; y[c * 4 + 1] = x.y;
        y[c * 4 + 2] = x.z; y[c * 4 + 3] = x.w;
        s  += x.x + x.y + x.z + x.w;
        ss += x.x * x.x + x.y * x.y + x.z * x.z + x.w * x.w;
    }
#pragma unroll
    for (int m = 1; m < 16; m <<= 1) { s += __shfl_xor(s, m); ss += __shfl_xor(ss, m); }
    const float mu   = s * (1.0f / (float)Hh);
    const float rstd = rsqrtf(ss * (1.0f / (float)Hh) - mu * mu + LN_EPS);
    const int hb = sub * 16;
#pragma unroll
    for (int c = 0; c < 4; ++c) {
        const float4 g  = *reinterpret_cast<const float4*>(gamma + hb + c * 4);
        const float4 bb = *reinterpret_cast<const float4*>(beta  + hb + c * 4);
        y[c * 4 + 0] = (y[c * 4 + 0] - mu) * rstd * g.x + bb.x;
        y[c * 4 + 1] = (y[c * 4 + 1] - mu) * rstd * g.y + bb.y;
        y[c * 4 + 2] = (y[c * 4 + 2] - mu) * rstd * g.z + bb.z;
        y[c * 4 + 3] = (y[c * 4 + 3] - mu) * rstd * g.w + bb.w;
    }
}

// ---------------- K1: wave per (b,n) — LN support, M, support scores ----------------
__global__ __launch_bounds__(256) void k1_M_scores(
    const float* __restrict__ support,
    const float* __restrict__ gamma, const float* __restrict__ beta,
    float* __restrict__ M, float* __restrict__ scores, int* __restrict__ cnt, int B)
{
    const int gtid = blockIdx.x * 256 + threadIdx.x;
    if (gtid < B * Nn) cnt[gtid] = 0;           // re-zero counts every launch
    const int gw = gtid >> 6;
    if (gw >= B * Nn) return;
    const int lane = threadIdx.x & 63;

    const float4 g4 = *reinterpret_cast<const float4*>(gamma + lane * 4);
    const float4 b4 = *reinterpret_cast<const float4*>(beta  + lane * 4);
    const float* rows = support + (size_t)gw * Kk * Hh;

    float y[Kk][4];
#pragma unroll
    for (int k = 0; k < Kk; ++k) {
        const float4 x = *reinterpret_cast<const float4*>(rows + k * Hh + lane * 4);
        ln64_x(x, g4, b4, y[k]);
    }
    float Mv[4];
#pragma unroll
    for (int i = 0; i < 4; ++i)
        Mv[i] = (y[0][i] + y[1][i] + y[2][i] + y[3][i] + y[4][i]) / 5.0f;
    *reinterpret_cast<float4*>(M + (size_t)gw * Hh + lane * 4) =
        make_float4(Mv[0], Mv[1], Mv[2], Mv[3]);
#pragma unroll
    for (int k = 0; k < Kk; ++k) {
        float p = y[k][0] * Mv[0] + y[k][1] * Mv[1] + y[k][2] * Mv[2] + y[k][3] * Mv[3];
        p = wave64_sum(p);
        if (lane == 0) scores[gw * Kk + k] = p;
    }
}

// ---------------- K2: 16-group per (b,q) — Cq, wq, counts ----------------
__global__ __launch_bounds__(256) void k2_assign(
    const float* __restrict__ query,
    const float* __restrict__ gamma, const float* __restrict__ beta,
    const float* __restrict__ M,
    float* __restrict__ wqv, int* __restrict__ cq, int* __restrict__ cnt, int B)
{
    const int gg = (blockIdx.x * 256 + threadIdx.x) >> 4;
    if (gg >= B * QT) return;
    const int sub = threadIdx.x & 15;
    const int b = gg / QT;

    float y16[16];
    ln16_row(query + (size_t)gg * Hh, gamma, beta, sub, y16);
    const int hb = sub * 16;
    const float* Mb = M + (size_t)b * Nn * Hh;

    float bestd = INFINITY; int bestn = 0;
#pragma unroll
    for (int n = 0; n < Nn; ++n) {
        const float* mrow = Mb + n * Hh + hb;
        float p = 0.f;
#pragma unroll
        for (int c = 0; c < 4; ++c) {
            const float4 mv = *reinterpret_cast<const float4*>(mrow + c * 4);
            float d0 = y16[c * 4 + 0] - mv.x; p = fmaf(d0, d0, p);
            float d1 = y16[c * 4 + 1] - mv.y; p = fmaf(d1, d1, p);
            float d2 = y16[c * 4 + 2] - mv.z; p = fmaf(d2, d2, p);
            float d3 = y16[c * 4 + 3] - mv.w; p = fmaf(d3, d3, p);
        }
        p = grp16_sum(p);
        if (p < bestd) { bestd = p; bestn = n; }   // first-index tie-break
    }
    const float* mrow = Mb + bestn * Hh + hb;
    float sc = 0.f;
#pragma unroll
    for (int c = 0; c < 4; ++c) {
        const float4 mv = *reinterpret_cast<const float4*>(mrow + c * 4);
        sc = fmaf(y16[c * 4 + 0], mv.x, sc);
        sc = fmaf(y16[c * 4 + 1], mv.y, sc);
        sc = fmaf(y16[c * 4 + 2], mv.z, sc);
        sc = fmaf(y16[c * 4 + 3], mv.w, sc);
    }
    sc = grp16_sum(sc);
    if (sub == 0) {
        // softmax over N at this slot: {sc} ∪ {0}×(N-1), max-subtracted
        const float mx  = fmaxf(sc, 0.f);
        const float e   = expf(sc - mx);
        const float den = e + (float)(Nn - 1) * expf(-mx);
        wqv[gg] = e / den;
        cq[gg]  = bestn;
        atomicAdd(&cnt[b * Nn + bestn], 1);
    }
}

// ---------------- K3: wave per (b,n) — rectified prototype ----------------
__global__ __launch_bounds__(256) void k3_proto(
    const float* __restrict__ support, const float* __restrict__ query,
    const float* __restrict__ gamma, const float* __restrict__ beta,
    const float* __restrict__ scores, const float* __restrict__ wqv,
    const int* __restrict__ cq, const int* __restrict__ cnt,
    float* __restrict__ proto, int B)
{
    const int gw = (blockIdx.x * 256 + threadIdx.x) >> 6;
    if (gw >= B * Nn) return;
    const int lane = threadIdx.x & 63;
    const int b = gw / Nn, n = gw % Nn;

    // per-k softmax weight over N (lanes 0..K-1 each own one k)
    float w = 0.f;
    if (lane < Kk) {
        const float* sc = scores + (size_t)b * Nn * Kk + lane;  // stride K over n
        float mx = -INFINITY;
#pragma unroll
        for (int nn = 0; nn < Nn; ++nn) mx = fmaxf(mx, sc[nn * Kk]);
        float den = 0.f, mye = 0.f;
#pragma unroll
        for (int nn = 0; nn < Nn; ++nn) {
            const float e = expf(sc[nn * Kk] - mx);
            den += e;
            if (nn == n) mye = e;
        }
        w = mye / den;
    }

    const float4 g4 = *reinterpret_cast<const float4*>(gamma + lane * 4);
    const float4 b4 = *reinterpret_cast<const float4*>(beta  + lane * 4);
    const float* rows = support + (size_t)gw * Kk * Hh;

    float acc[4] = {0.f, 0.f, 0.f, 0.f};
#pragma unroll
    for (int k = 0; k < Kk; ++k) {
        const float wk = __shfl(w, k);
        const float4 x = *reinterpret_cast<const float4*>(rows + k * Hh + lane * 4);
        float y[4];
        ln64_x(x, g4, b4, y);
#pragma unroll
        for (int i = 0; i < 4; ++i) acc[i] = fmaf(wk, y[i], acc[i]);
    }

    // rectification: queries assigned to this proto
    int   myc = -1; float myw = 0.f;
    if (lane < QT) { myc = cq[b * QT + lane]; myw = wqv[b * QT + lane]; }
    for (int q = 0; q < QT; ++q) {
        if (__shfl(myc, q) == n) {          // wave-uniform branch
            const float wq = __shfl(myw, q);
            const float4 x = *reinterpret_cast<const float4*>(
                query + ((size_t)b * QT + q) * Hh + lane * 4);
            float y[4];
            ln64_x(x, g4, b4, y);
#pragma unroll
            for (int i = 0; i < 4; ++i) acc[i] = fmaf(wq, y[i], acc[i]);
        }
    }
    const float size = (float)(Kk + cnt[gw]);
    *reinterpret_cast<float4*>(proto + (size_t)gw * Hh + lane * 4) =
        make_float4(acc[0] / size, acc[1] / size, acc[2] / size, acc[3] / size);
}

// ---------------- K4: 16-group per (b,q) — logits + pred ----------------
__global__ __launch_bounds__(256) void k4_logits(
    const float* __restrict__ query,
    const float* __restrict__ gamma, const float* __restrict__ beta,
    const float* __restrict__ proto, float* __restrict__ out, int B)
{
    const int gg = (blockIdx.x * 256 + threadIdx.x) >> 4;
    if (gg >= B * QT) return;
    const int sub = threadIdx.x & 15;
    const int b = gg / QT;

    float y16[16];
    ln16_row(query + (size_t)gg * Hh, gamma, beta, sub, y16);
    const int hb = sub * 16;
    const float* Pb = proto + (size_t)b * Nn * Hh;

    float d[Nn];
    float maxd = -INFINITY, bestd = INFINITY;
    int bestn = 0;
#pragma unroll
    for (int n = 0; n < Nn; ++n) {
        const float* pr = Pb + n * Hh + hb;
        float p = 0.f;
#pragma unroll
        for (int c = 0; c < 4; ++c) {
            const float4 pv = *reinterpret_cast<const float4*>(pr + c * 4);
            float d0 = y16[c * 4 + 0] - pv.x; p = fmaf(d0, d0, p);
            float d1 = y16[c * 4 + 1] - pv.y; p = fmaf(d1, d1, p);
            float d2 = y16[c * 4 + 2] - pv.z; p = fmaf(d2, d2, p);
            float d3 = y16[c * 4 + 3] - pv.w; p = fmaf(d3, d3, p);
        }
        p = grp16_sum(p);
        d[n] = p;
        maxd = fmaxf(maxd, p);
        if (p < bestd) { bestd = p; bestn = n; }
    }
    if (sub == 0) {
        float* o = out + (size_t)gg * NP1;
#pragma unroll
        for (int n = 0; n < Nn; ++n) o[n] = -d[n];
        o[Nn] = -maxd - 1.0f;                       // min(logits) - 1
        out[(size_t)B * QT * NP1 + gg] = (float)bestn;
    }
}

extern "C" void kernel_launch(void* const* d_in, const int* in_sizes, int n_in,
                              void* d_out, int out_size, void* d_ws, size_t ws_size,
                              hipStream_t stream) {
    const float* support = (const float*)d_in[0];
    const float* query   = (const float*)d_in[1];
    const float* gamma   = (const float*)d_in[2];
    const float* beta    = (const float*)d_in[3];
    float* out = (float*)d_out;

    const int B = in_sizes[0] / (Nn * Kk * Hh);   // 512

    // workspace layout (floats): M | proto | scores | wq | cq | cnt  (~10.7 MB)
    float* M      = (float*)d_ws;
    float* proto  = M + (size_t)B * Nn * Hh;
    float* scores = proto + (size_t)B * Nn * Hh;
    float* wqv    = scores + (size_t)B * Nn * Kk;
    int*   cq     = (int*)(wqv + (size_t)B * QT);
    int*   cnt    = cq + (size_t)B * QT;

    const int waves_bn  = B * Nn;                 // 5120
    const int grps_bq   = B * QT;                 // 25600
    const int blk1 = (waves_bn * 64 + 255) / 256; // 1280
    const int blk2 = (grps_bq * 16 + 255) / 256;  // 1600

    k1_M_scores<<<blk1, 256, 0, stream>>>(support, gamma, beta, M, scores, cnt, B);
    k2_assign  <<<blk2, 256, 0, stream>>>(query, gamma, beta, M, wqv, cq, cnt, B);
    k3_proto   <<<blk1, 256, 0, stream>>>(support, query, gamma, beta,
                                          scores, wqv, cq, cnt, proto, B);
    k4_logits  <<<blk2, 256, 0, stream>>>(query, gamma, beta, proto, out, B);
}

// Round 3
// 34.773 us; speedup vs baseline: 2.4193x; 2.4193x over previous
//
#include <hip/hip_runtime.h>
#include <math.h>

#define LN_EPS 1e-5f

// Problem constants (fixed by setup_inputs): N=10, K=5, Q=5, H=256, Qtot=50
constexpr int Nn  = 10;
constexpr int Kk  = 5;
constexpr int Hh  = 256;
constexpr int QT  = 50;
constexpr int NP1 = 11;

__device__ __forceinline__ float grp16_sum(float v) {
#pragma unroll
    for (int m = 1; m < 16; m <<= 1) v += __shfl_xor(v, m);
    return v;
}

// Fused single kernel: one batch per 1024-thread block (16 waves).
// Phases:
//   A  (waves 0-9):  LN support rows (stats->LDS), prototype M, support scores
//   A' (waves 10-15): query LN stats (mu,rstd) -> LDS
//   C  (groups 0-49): nearest-M assignment Cq, query weight wq, counts
//   B  (groups 56-60, sub0): per-k softmax over N of support scores
//   E  (waves 0-9):  rectified prototype (LN recomputed from stats, no butterflies)
//   F  (groups 0-49): distances to proto -> logits + pred
// LDS reads in 16-lane phases use permuted h-ownership (sub owns h = c*64+sub*4+j)
// so every access is 16 contiguous float4s -> conflict-free.
__global__ __launch_bounds__(1024, 8) void proto_rectify_fused(
    const float* __restrict__ support, const float* __restrict__ query,
    const float* __restrict__ gamma,   const float* __restrict__ beta,
    float* __restrict__ out, int B)
{
    const int b    = blockIdx.x;
    const int tid  = threadIdx.x;
    const int lane = tid & 63;
    const int wave = tid >> 6;   // 0..15
    const int grp  = tid >> 4;   // 0..63
    const int sub  = tid & 15;

    __shared__ float g_s[Hh], bt_s[Hh];
    __shared__ float M_s[Nn][Hh];
    __shared__ float proto_s[Nn][Hh];
    __shared__ float score_s[Nn * Kk];
    __shared__ float wsup_s[Nn * Kk];
    __shared__ float wq_s[QT];
    __shared__ int   cq_s[QT];
    __shared__ float sstat_s[Nn * Kk][2];  // per support row: mu, rstd
    __shared__ float qstat_s[QT][2];       // per query row:   mu, rstd
    __shared__ int   cnt_s[Nn];

    if (tid < Hh)                 g_s[tid]        = gamma[tid];
    else if (tid < 2 * Hh)        bt_s[tid - Hh]  = beta[tid - Hh];
    if (tid < Nn)                 cnt_s[tid]      = 0;
    __syncthreads();

    const float* supB = support + (size_t)b * (Nn * Kk * Hh);
    const float* qryB = query   + (size_t)b * (QT * Hh);

    // ---------------- Phase A / A' ----------------
    if (wave < Nn) {
        const int n = wave;
        const float4 g4 = *reinterpret_cast<const float4*>(g_s  + lane * 4);
        const float4 b4 = *reinterpret_cast<const float4*>(bt_s + lane * 4);
        const float* rows = supB + (size_t)n * Kk * Hh;

        float y[Kk][4];
#pragma unroll
        for (int k = 0; k < Kk; ++k) {
            const float4 x = *reinterpret_cast<const float4*>(rows + k * Hh + lane * 4);
            float s  = x.x + x.y + x.z + x.w;
            float ss = x.x * x.x + x.y * x.y + x.z * x.z + x.w * x.w;
#pragma unroll
            for (int m = 1; m < 64; m <<= 1) { s += __shfl_xor(s, m); ss += __shfl_xor(ss, m); }
            const float mu   = s * (1.0f / (float)Hh);
            const float rstd = rsqrtf(ss * (1.0f / (float)Hh) - mu * mu + LN_EPS);
            if (lane == 0) { sstat_s[n * Kk + k][0] = mu; sstat_s[n * Kk + k][1] = rstd; }
            y[k][0] = (x.x - mu) * rstd * g4.x + b4.x;
            y[k][1] = (x.y - mu) * rstd * g4.y + b4.y;
            y[k][2] = (x.z - mu) * rstd * g4.z + b4.z;
            y[k][3] = (x.w - mu) * rstd * g4.w + b4.w;
        }
        float Mv[4];
#pragma unroll
        for (int i = 0; i < 4; ++i)
            Mv[i] = (y[0][i] + y[1][i] + y[2][i] + y[3][i] + y[4][i]) / 5.0f;
        *reinterpret_cast<float4*>(&M_s[n][lane * 4]) =
            make_float4(Mv[0], Mv[1], Mv[2], Mv[3]);
#pragma unroll
        for (int k = 0; k < Kk; ++k) {
            float p = y[k][0] * Mv[0] + y[k][1] * Mv[1] + y[k][2] * Mv[2] + y[k][3] * Mv[3];
#pragma unroll
            for (int m = 1; m < 64; m <<= 1) p += __shfl_xor(p, m);
            if (lane == 0) score_s[n * Kk + k] = p;
        }
    } else {
        // waves 10..15 -> groups 40..63 (24 groups): query LN stats
        for (int q = grp - 40; q < QT; q += 24) {
            const float* row = qryB + (size_t)q * Hh;
            float s = 0.f, ss = 0.f;
#pragma unroll
            for (int c = 0; c < 4; ++c) {
                const float4 x = *reinterpret_cast<const float4*>(row + c * 64 + sub * 4);
                s  += x.x + x.y + x.z + x.w;
                ss += x.x * x.x + x.y * x.y + x.z * x.z + x.w * x.w;
            }
            s  = grp16_sum(s);
            ss = grp16_sum(ss);
            if (sub == 0) {
                const float mu = s * (1.0f / (float)Hh);
                qstat_s[q][0] = mu;
                qstat_s[q][1] = rsqrtf(ss * (1.0f / (float)Hh) - mu * mu + LN_EPS);
            }
        }
    }
    __syncthreads();

    // ---------------- Phase C (groups 0-49) + B (groups 56-60) ----------------
    if (grp < QT) {
        const int q = grp;
        const float* row  = qryB + (size_t)q * Hh;
        const float  mu   = qstat_s[q][0];
        const float  rstd = qstat_s[q][1];
        float y16[16];
#pragma unroll
        for (int c = 0; c < 4; ++c) {
            const int h = c * 64 + sub * 4;
            const float4 x  = *reinterpret_cast<const float4*>(row + h);
            const float4 gg = *reinterpret_cast<const float4*>(g_s + h);
            const float4 bb = *reinterpret_cast<const float4*>(bt_s + h);
            y16[c * 4 + 0] = (x.x - mu) * rstd * gg.x + bb.x;
            y16[c * 4 + 1] = (x.y - mu) * rstd * gg.y + bb.y;
            y16[c * 4 + 2] = (x.z - mu) * rstd * gg.z + bb.z;
            y16[c * 4 + 3] = (x.w - mu) * rstd * gg.w + bb.w;
        }
        float bestd = INFINITY; int bestn = 0;
#pragma unroll
        for (int n = 0; n < Nn; ++n) {
            float p = 0.f;
#pragma unroll
            for (int c = 0; c < 4; ++c) {
                const float4 mv = *reinterpret_cast<const float4*>(&M_s[n][c * 64 + sub * 4]);
                float d0 = y16[c * 4 + 0] - mv.x; p = fmaf(d0, d0, p);
                float d1 = y16[c * 4 + 1] - mv.y; p = fmaf(d1, d1, p);
                float d2 = y16[c * 4 + 2] - mv.z; p = fmaf(d2, d2, p);
                float d3 = y16[c * 4 + 3] - mv.w; p = fmaf(d3, d3, p);
            }
            p = grp16_sum(p);
            if (p < bestd) { bestd = p; bestn = n; }   // first-index tie-break
        }
        float sc = 0.f;
#pragma unroll
        for (int c = 0; c < 4; ++c) {
            const float4 mv = *reinterpret_cast<const float4*>(&M_s[bestn][c * 64 + sub * 4]);
            sc = fmaf(y16[c * 4 + 0], mv.x, sc);
            sc = fmaf(y16[c * 4 + 1], mv.y, sc);
            sc = fmaf(y16[c * 4 + 2], mv.z, sc);
            sc = fmaf(y16[c * 4 + 3], mv.w, sc);
        }
        sc = grp16_sum(sc);
        if (sub == 0) {
            // softmax over N at this slot: {sc} U {0}x(N-1), max-subtracted
            const float mx  = fmaxf(sc, 0.f);
            const float e   = expf(sc - mx);
            const float den = e + (float)(Nn - 1) * expf(-mx);
            wq_s[q] = e / den;
            cq_s[q] = bestn;
            atomicAdd(&cnt_s[bestn], 1);
        }
    } else if (grp >= 56 && grp < 56 + Kk && sub == 0) {
        const int k = grp - 56;
        float mx = -INFINITY;
#pragma unroll
        for (int n = 0; n < Nn; ++n) mx = fmaxf(mx, score_s[n * Kk + k]);
        float e[Nn]; float den = 0.f;
#pragma unroll
        for (int n = 0; n < Nn; ++n) { e[n] = expf(score_s[n * Kk + k] - mx); den += e[n]; }
#pragma unroll
        for (int n = 0; n < Nn; ++n) wsup_s[n * Kk + k] = e[n] / den;
    }
    __syncthreads();

    // ---------------- Phase E (waves 0-9): rectified prototype ----------------
    if (wave < Nn) {
        const int n = wave;
        const float4 g4 = *reinterpret_cast<const float4*>(g_s  + lane * 4);
        const float4 b4 = *reinterpret_cast<const float4*>(bt_s + lane * 4);
        const float* rows = supB + (size_t)n * Kk * Hh;

        float acc[4] = {0.f, 0.f, 0.f, 0.f};
#pragma unroll
        for (int k = 0; k < Kk; ++k) {
            const float w    = wsup_s[n * Kk + k];
            const float mu   = sstat_s[n * Kk + k][0];
            const float rstd = sstat_s[n * Kk + k][1];
            const float4 x = *reinterpret_cast<const float4*>(rows + k * Hh + lane * 4);
            acc[0] = fmaf(w, (x.x - mu) * rstd * g4.x + b4.x, acc[0]);
            acc[1] = fmaf(w, (x.y - mu) * rstd * g4.y + b4.y, acc[1]);
            acc[2] = fmaf(w, (x.z - mu) * rstd * g4.z + b4.z, acc[2]);
            acc[3] = fmaf(w, (x.w - mu) * rstd * g4.w + b4.w, acc[3]);
        }
        for (int q = 0; q < QT; ++q) {
            if (cq_s[q] == n) {                        // wave-uniform branch
                const float w    = wq_s[q];
                const float mu   = qstat_s[q][0];
                const float rstd = qstat_s[q][1];
                const float4 x = *reinterpret_cast<const float4*>(qryB + (size_t)q * Hh + lane * 4);
                acc[0] = fmaf(w, (x.x - mu) * rstd * g4.x + b4.x, acc[0]);
                acc[1] = fmaf(w, (x.y - mu) * rstd * g4.y + b4.y, acc[1]);
                acc[2] = fmaf(w, (x.z - mu) * rstd * g4.z + b4.z, acc[2]);
                acc[3] = fmaf(w, (x.w - mu) * rstd * g4.w + b4.w, acc[3]);
            }
        }
        const float inv = 1.0f / (float)(Kk + cnt_s[n]);
        *reinterpret_cast<float4*>(&proto_s[n][lane * 4]) =
            make_float4(acc[0] * inv, acc[1] * inv, acc[2] * inv, acc[3] * inv);
    }
    __syncthreads();

    // ---------------- Phase F (groups 0-49): logits + pred ----------------
    if (grp < QT) {
        const int q = grp;
        const float* row  = qryB + (size_t)q * Hh;
        const float  mu   = qstat_s[q][0];
        const float  rstd = qstat_s[q][1];
        float y16[16];
#pragma unroll
        for (int c = 0; c < 4; ++c) {
            const int h = c * 64 + sub * 4;
            const float4 x  = *reinterpret_cast<const float4*>(row + h);
            const float4 gg = *reinterpret_cast<const float4*>(g_s + h);
            const float4 bb = *reinterpret_cast<const float4*>(bt_s + h);
            y16[c * 4 + 0] = (x.x - mu) * rstd * gg.x + bb.x;
            y16[c * 4 + 1] = (x.y - mu) * rstd * gg.y + bb.y;
            y16[c * 4 + 2] = (x.z - mu) * rstd * gg.z + bb.z;
            y16[c * 4 + 3] = (x.w - mu) * rstd * gg.w + bb.w;
        }
        float mine = 0.f, maxd = -INFINITY, bestd = INFINITY;
        int bestn = 0;
#pragma unroll
        for (int n = 0; n < Nn; ++n) {
            float p = 0.f;
#pragma unroll
            for (int c = 0; c < 4; ++c) {
                const float4 pv = *reinterpret_cast<const float4*>(&proto_s[n][c * 64 + sub * 4]);
                float d0 = y16[c * 4 + 0] - pv.x; p = fmaf(d0, d0, p);
                float d1 = y16[c * 4 + 1] - pv.y; p = fmaf(d1, d1, p);
                float d2 = y16[c * 4 + 2] - pv.z; p = fmaf(d2, d2, p);
                float d3 = y16[c * 4 + 3] - pv.w; p = fmaf(d3, d3, p);
            }
            p = grp16_sum(p);                 // full butterfly: all 16 lanes hold p
            if (sub == n) mine = p;
            maxd = fmaxf(maxd, p);
            if (p < bestd) { bestd = p; bestn = n; }
        }
        float* o = out + ((size_t)b * QT + q) * NP1;
        if (sub < Nn)       o[sub] = -mine;
        else if (sub == Nn) o[Nn]  = -maxd - 1.0f;             // min(logits) - 1
        else if (sub == Nn + 1)
            out[(size_t)B * QT * NP1 + (size_t)b * QT + q] = (float)bestn;
    }
}

extern "C" void kernel_launch(void* const* d_in, const int* in_sizes, int n_in,
                              void* d_out, int out_size, void* d_ws, size_t ws_size,
                              hipStream_t stream) {
    const float* support = (const float*)d_in[0];
    const float* query   = (const float*)d_in[1];
    const float* gamma   = (const float*)d_in[2];
    const float* beta    = (const float*)d_in[3];
    float* out = (float*)d_out;

    const int B = in_sizes[0] / (Nn * Kk * Hh);   // 512
    proto_rectify_fused<<<B, 1024, 0, stream>>>(support, query, gamma, beta, out, B);
}